// Round 1
// baseline (223.861 us; speedup 1.0000x reference)
//
#include <hip/hip_runtime.h>
#include <stdint.h>

typedef unsigned long long u64;

#define VOX     32768      // 32*32*32
#define KCAP    512        // candidate cap (matches reference K)
#define MAXEV   100        // max_events
#define NBRCAP  26         // geometric max conflicts per point (26-neighborhood)
#define THREADS 256

// dist < 2.0 on integer coords  <=>  Chebyshev distance <= 1 (3x3x3 cube)

__global__ __launch_bounds__(THREADS) void event_filter_kernel(
    const float* __restrict__ x, float* __restrict__ out)
{
    const int f   = blockIdx.x;
    const int tid = threadIdx.x;
    const float* __restrict__ e  = x   + (size_t)f * 2 * VOX;   // energy channel
    const float* __restrict__ mg = e   + VOX;                   // magnitude channel
    float* __restrict__ oe = out + (size_t)f * 2 * VOX;
    float* __restrict__ om = oe + VOX;

    __shared__ float sval[KCAP];
    __shared__ int   sidx[KCAP];
    __shared__ int   ncnt[KCAP];
    __shared__ unsigned short nbr[KCAP * NBRCAP];
    __shared__ u64   skeep[KCAP / 64];
    __shared__ int   s_cntpos;
    __shared__ int   s_cntnz;

    if (tid == 0) { s_cntpos = 0; s_cntnz = 0; }
    __syncthreads();

    // ---- Phase A: zero-fill own frame's output + collect positive voxels ----
    {
        const float4* e4  = (const float4*)e;
        float4*       oe4 = (float4*)oe;
        const float4  z   = make_float4(0.f, 0.f, 0.f, 0.f);
        #pragma unroll 4
        for (int i = tid; i < 2 * VOX / 4; i += THREADS) oe4[i] = z;

        int nzloc = 0;
        for (int i = tid; i < VOX / 4; i += THREADS) {
            float4 v = e4[i];
            float vv[4] = {v.x, v.y, v.z, v.w};
            #pragma unroll
            for (int c = 0; c < 4; ++c) {
                float val = vv[c];
                if (val != 0.f) {
                    nzloc++;
                    if (val > 0.f) {
                        int slot = atomicAdd(&s_cntpos, 1);
                        if (slot < KCAP) { sval[slot] = val; sidx[slot] = i * 4 + c; }
                    }
                }
            }
        }
        if (nzloc) atomicAdd(&s_cntnz, nzloc);
    }
    __syncthreads();

    const int npos  = min(s_cntpos, KCAP);
    const int anynz = s_cntnz;

    // pad the sort array
    for (int i = npos + tid; i < KCAP; i += THREADS) {
        sval[i] = -1.0f;
        sidx[i] = 0x40000000 + i;
    }
    __syncthreads();

    // ---- Phase B: bitonic sort, descending by value, tie-break idx ascending
    // (matches lax.top_k stability: equal values -> lower index first)
    for (int k = 2; k <= KCAP; k <<= 1) {
        for (int j = k >> 1; j > 0; j >>= 1) {
            #pragma unroll
            for (int half = 0; half < KCAP / THREADS; ++half) {
                int t   = tid + half * THREADS;
                int ixj = t ^ j;
                if (ixj > t) {
                    float va = sval[t], vb = sval[ixj];
                    int   ia = sidx[t], ib = sidx[ixj];
                    bool a_first = (va > vb) || (va == vb && ia < ib);
                    bool up      = ((t & k) == 0);
                    if (up != a_first) {
                        sval[t] = vb; sval[ixj] = va;
                        sidx[t] = ib; sidx[ixj] = ia;
                    }
                }
            }
            __syncthreads();
        }
    }

    // ---- Phase C: adjacency — for each conflicting pair i<j append j to nbr[i]
    for (int i = tid; i < KCAP; i += THREADS) ncnt[i] = 0;
    __syncthreads();

    for (int j = tid; j < npos; j += THREADS) {
        int vj = sidx[j];
        int zj = vj >> 10, yj = (vj >> 5) & 31, xj = vj & 31;
        for (int i = 0; i < j; ++i) {
            int vi = sidx[i];
            int dz = (vi >> 10)       - zj; if (dz < 0) dz = -dz;
            int dy = ((vi >> 5) & 31) - yj; if (dy < 0) dy = -dy;
            int dx = (vi & 31)        - xj; if (dx < 0) dx = -dx;
            if ((dz | dy | dx) <= 1) {   // all of dz,dy,dx in {0,1}
                int p = atomicAdd(&ncnt[i], 1);
                if (p < NBRCAP) nbr[i * NBRCAP + p] = (unsigned short)j;
            }
        }
    }
    __syncthreads();

    // ---- Phase D: sequential greedy NMS (thread 0), keep-bits in registers ----
    if (tid == 0) {
        u64 km[8];
        #pragma unroll
        for (int w = 0; w < 8; ++w) {
            int lo = w * 64;
            u64 m;
            if      (npos >= lo + 64) m = ~0ull;
            else if (npos <= lo)      m = 0ull;
            else                      m = (((u64)1) << (npos - lo)) - 1;
            km[w] = m;
        }
        int kept = 0;
        #pragma unroll
        for (int w = 0; w < 8; ++w) {
            if (km[w]) {
                for (int b = 0; b < 64; ++b) {
                    int i = (w << 6) + b;
                    int c = ncnt[i];                 // unconditional: pipelines
                    if ((km[w] >> b) & 1) {
                        kept++;
                        for (int p = 0; p < c; ++p) {
                            int j  = nbr[i * NBRCAP + p];
                            u64 bm = ~(((u64)1) << (j & 63));
                            int wj = j >> 6;
                            #pragma unroll
                            for (int w2 = 0; w2 < 8; ++w2)
                                if (w2 >= w && wj == w2) km[w2] &= bm;
                        }
                    }
                }
            }
        }
        // truncation rule: if more than MAXEV kept, drop everything at sorted
        // position >= MAXEV (MAXEV=100 -> word 1, bit 36)
        if (kept > MAXEV) {
            km[1] &= (((u64)1) << (MAXEV - 64)) - 1;
            #pragma unroll
            for (int w = 2; w < 8; ++w) km[w] = 0;
        }
        #pragma unroll
        for (int w = 0; w < 8; ++w) skeep[w] = km[w];
    }
    __syncthreads();

    // ---- Phase E: output ----
    if (anynz == 0) {
        // empty frame passes through unchanged
        const float4* x4 = (const float4*)e;
        float4*       o4 = (float4*)oe;
        for (int i = tid; i < 2 * VOX / 4; i += THREADS) o4[i] = x4[i];
    } else {
        for (int i = tid; i < npos; i += THREADS) {
            if ((skeep[i >> 6] >> (i & 63)) & 1) {
                int vox = sidx[i];
                oe[vox] = sval[i];      // energy * 1 (exact copy)
                om[vox] = mg[vox];      // magnitude * 1 (exact copy)
            }
        }
    }
}

extern "C" void kernel_launch(void* const* d_in, const int* in_sizes, int n_in,
                              void* d_out, int out_size, void* d_ws, size_t ws_size,
                              hipStream_t stream) {
    const float* x = (const float*)d_in[0];
    float* out = (float*)d_out;
    int frames = in_sizes[0] / (2 * VOX);   // B*T = 256
    event_filter_kernel<<<frames, THREADS, 0, stream>>>(x, out);
}

// Round 2
// 198.549 us; speedup vs baseline: 1.1275x; 1.1275x over previous
//
#include <hip/hip_runtime.h>
#include <stdint.h>

typedef unsigned long long u64;

#define VOX     32768      // 32*32*32
#define KCAP    512        // candidate cap (matches reference K)
#define MAXEV   100        // max_events
#define NBRCAP  26         // geometric max conflicts per point (26-neighborhood)
#define NMS_THREADS 1024
#define OUT_THREADS 256
#define CHUNKS  8
#define CHUNK_FLOATS (2 * VOX / CHUNKS)   // 8192 floats = 32 KB per chunk
#define MAXSURV 128

struct Surv { int vox; float val; };

// dist < 2.0 on integer coords  <=>  Chebyshev distance <= 1 (3x3x3 cube)

// ---------------------------------------------------------------------------
// Kernel 1: per-frame NMS -> compact survivor list in workspace.
// nsurv[f] = -1 means "empty frame, pass through input unchanged".
// ---------------------------------------------------------------------------
__global__ __launch_bounds__(NMS_THREADS) void nms_kernel(
    const float* __restrict__ x, int* __restrict__ nsurv, Surv* __restrict__ surv)
{
    const int f   = blockIdx.x;
    const int tid = threadIdx.x;
    const float* __restrict__ e = x + (size_t)f * 2 * VOX;   // energy channel

    __shared__ float sval[KCAP];
    __shared__ int   sidx[KCAP];
    __shared__ int   ncnt[KCAP];
    __shared__ unsigned short nbr[KCAP * NBRCAP];
    __shared__ u64   skeep[KCAP / 64];
    __shared__ int   s_cntpos;
    __shared__ int   s_cntnz;
    __shared__ int   s_nk;

    if (tid == 0) { s_cntpos = 0; s_cntnz = 0; s_nk = 0; }
    __syncthreads();

    // ---- Phase A: collect positive voxels (pure read; 16 waves of MLP) ----
    {
        const float4* e4 = (const float4*)e;
        int nzloc = 0;
        #pragma unroll
        for (int h = 0; h < VOX / 4 / NMS_THREADS; ++h) {
            int i = tid + h * NMS_THREADS;
            float4 v = e4[i];
            float vv[4] = {v.x, v.y, v.z, v.w};
            #pragma unroll
            for (int c = 0; c < 4; ++c) {
                float val = vv[c];
                if (val != 0.f) {
                    nzloc++;
                    if (val > 0.f) {
                        int slot = atomicAdd(&s_cntpos, 1);
                        if (slot < KCAP) { sval[slot] = val; sidx[slot] = i * 4 + c; }
                    }
                }
            }
        }
        if (nzloc) atomicAdd(&s_cntnz, nzloc);
    }
    __syncthreads();

    const int npos  = min(s_cntpos, KCAP);
    const int anynz = s_cntnz;

    // pad the sort array
    for (int i = npos + tid; i < KCAP; i += NMS_THREADS) {
        sval[i] = -1.0f;
        sidx[i] = 0x40000000 + i;
    }
    __syncthreads();

    // ---- Phase B: bitonic sort, descending by value, tie-break idx ascending
    // (matches lax.top_k stability: equal values -> lower index first)
    for (int k = 2; k <= KCAP; k <<= 1) {
        for (int j = k >> 1; j > 0; j >>= 1) {
            if (tid < KCAP) {
                int t   = tid;
                int ixj = t ^ j;
                if (ixj > t) {
                    float va = sval[t], vb = sval[ixj];
                    int   ia = sidx[t], ib = sidx[ixj];
                    bool a_first = (va > vb) || (va == vb && ia < ib);
                    bool up      = ((t & k) == 0);
                    if (up != a_first) {
                        sval[t] = vb; sval[ixj] = va;
                        sidx[t] = ib; sidx[ixj] = ia;
                    }
                }
            }
            __syncthreads();
        }
    }

    // ---- Phase C: adjacency — for each conflicting pair i<j append j to nbr[i]
    for (int i = tid; i < KCAP; i += NMS_THREADS) ncnt[i] = 0;
    __syncthreads();

    if (tid < npos) {
        int j  = tid;
        int vj = sidx[j];
        int zj = vj >> 10, yj = (vj >> 5) & 31, xj = vj & 31;
        for (int i = 0; i < j; ++i) {
            int vi = sidx[i];                 // lockstep i -> LDS broadcast
            int dz = (vi >> 10)       - zj; if (dz < 0) dz = -dz;
            int dy = ((vi >> 5) & 31) - yj; if (dy < 0) dy = -dy;
            int dx = (vi & 31)        - xj; if (dx < 0) dx = -dx;
            if ((dz | dy | dx) <= 1) {        // all of dz,dy,dx in {0,1}
                int p = atomicAdd(&ncnt[i], 1);
                if (p < NBRCAP) nbr[i * NBRCAP + p] = (unsigned short)j;
            }
        }
    }
    __syncthreads();

    // ---- Phase D: sequential greedy NMS (thread 0), keep-bits in registers ----
    if (tid == 0) {
        u64 km[8];
        #pragma unroll
        for (int w = 0; w < 8; ++w) {
            int lo = w * 64;
            u64 m;
            if      (npos >= lo + 64) m = ~0ull;
            else if (npos <= lo)      m = 0ull;
            else                      m = (((u64)1) << (npos - lo)) - 1;
            km[w] = m;
        }
        int kept = 0;
        #pragma unroll
        for (int w = 0; w < 8; ++w) {
            if (km[w]) {
                for (int b = 0; b < 64; ++b) {
                    int i = (w << 6) + b;
                    int c = ncnt[i];                 // unconditional: pipelines
                    if ((km[w] >> b) & 1) {
                        kept++;
                        for (int p = 0; p < c; ++p) {
                            int j  = nbr[i * NBRCAP + p];
                            u64 bm = ~(((u64)1) << (j & 63));
                            int wj = j >> 6;
                            #pragma unroll
                            for (int w2 = 0; w2 < 8; ++w2)
                                if (w2 >= w && wj == w2) km[w2] &= bm;
                        }
                    }
                }
            }
        }
        // truncation rule: if more than MAXEV kept, drop everything at sorted
        // position >= MAXEV (MAXEV=100 -> word 1, bit 36)
        if (kept > MAXEV) {
            km[1] &= (((u64)1) << (MAXEV - 64)) - 1;
            #pragma unroll
            for (int w = 2; w < 8; ++w) km[w] = 0;
        }
        #pragma unroll
        for (int w = 0; w < 8; ++w) skeep[w] = km[w];
    }
    __syncthreads();

    // ---- Phase E: compact survivors to workspace ----
    if (tid < npos) {
        if ((skeep[tid >> 6] >> (tid & 63)) & 1) {
            int slot = atomicAdd(&s_nk, 1);
            Surv s; s.vox = sidx[tid]; s.val = sval[tid];
            surv[f * MAXSURV + slot] = s;
        }
    }
    __syncthreads();
    if (tid == 0) nsurv[f] = anynz ? s_nk : -1;
}

// ---------------------------------------------------------------------------
// Kernel 2: build output. Grid = frames*CHUNKS blocks; each block owns a
// 32 KB chunk of one frame's [2,V] output: zero it (or copy input for empty
// frames), then scatter the survivors that land in this chunk.
// ---------------------------------------------------------------------------
__global__ __launch_bounds__(OUT_THREADS) void output_kernel(
    const float* __restrict__ x, const int* __restrict__ nsurv,
    const Surv* __restrict__ surv, float* __restrict__ out)
{
    const int bid = blockIdx.x;
    const int f   = bid / CHUNKS;
    const int c   = bid % CHUNKS;
    const int tid = threadIdx.x;

    const float* __restrict__ xf = x   + (size_t)f * 2 * VOX;
    float*       __restrict__ of = out + (size_t)f * 2 * VOX;
    const int base = c * CHUNK_FLOATS;
    const int ns   = nsurv[f];

    if (ns < 0) {
        // empty frame: pass through input unchanged
        const float4* x4 = (const float4*)(xf + base);
        float4*       o4 = (float4*)(of + base);
        #pragma unroll
        for (int h = 0; h < CHUNK_FLOATS / 4 / OUT_THREADS; ++h)
            o4[tid + h * OUT_THREADS] = x4[tid + h * OUT_THREADS];
        return;
    }

    // zero this chunk
    {
        float4* o4 = (float4*)(of + base);
        const float4 z = make_float4(0.f, 0.f, 0.f, 0.f);
        #pragma unroll
        for (int h = 0; h < CHUNK_FLOATS / 4 / OUT_THREADS; ++h)
            o4[tid + h * OUT_THREADS] = z;
    }
    __syncthreads();   // order zero-fill before scatter within the block

    // scatter survivors that fall in this chunk (ns <= 100 < OUT_THREADS)
    if (tid < ns) {
        Surv s = surv[f * MAXSURV + tid];
        int vox = s.vox;
        int ec  = vox >> 13;                  // energy chunk index (8192 floats)
        if (c == ec) {
            of[vox] = s.val;                  // exact energy copy
        } else if (c == ec + CHUNKS / 2) {
            of[VOX + vox] = xf[VOX + vox];    // exact magnitude copy
        }
    }
}

extern "C" void kernel_launch(void* const* d_in, const int* in_sizes, int n_in,
                              void* d_out, int out_size, void* d_ws, size_t ws_size,
                              hipStream_t stream) {
    const float* x = (const float*)d_in[0];
    float* out = (float*)d_out;
    int frames = in_sizes[0] / (2 * VOX);   // B*T = 256

    int*  nsurv = (int*)d_ws;
    Surv* surv  = (Surv*)((char*)d_ws + 4096);   // frames*4 <= 4096, keep aligned

    nms_kernel<<<frames, NMS_THREADS, 0, stream>>>(x, nsurv, surv);
    output_kernel<<<frames * CHUNKS, OUT_THREADS, 0, stream>>>(x, nsurv, surv, out);
}

// Round 3
// 174.861 us; speedup vs baseline: 1.2802x; 1.1355x over previous
//
#include <hip/hip_runtime.h>
#include <stdint.h>

typedef unsigned long long u64;

#define VOX     32768      // 32*32*32
#define KCAP    512        // candidate cap (matches reference K; npos <= NPTS=400)
#define MAXEV   100        // max_events
#define NBRCAP  26         // geometric max conflicts per point (26-neighborhood)
#define NMS_THREADS 1024
#define OUT_THREADS 256
#define CHUNKS  8
#define CHUNK_FLOATS (2 * VOX / CHUNKS)   // 8192 floats = 32 KB per chunk
#define MAXSURV 128

struct Surv { int vox; float val; };

// dist < 2.0 on integer coords  <=>  Chebyshev distance <= 1 (3x3x3 cube)

// ---------------------------------------------------------------------------
// Kernel 1: per-frame NMS -> compact survivor list in workspace.
// nsurv[f] = -1 means "empty frame, pass through input unchanged".
//
// Sort-free formulation:
//   rank[t]  = #points with higher priority (val desc, voxel-idx asc tiebreak)
//              == position in lax.top_k output (ranks are unique).
//   greedy NMS == fixpoint of: kept iff all higher-priority conflicting
//              points are suppressed. Status updates are monotone
//              (undecided -> kept/suppressed exactly once), so parallel
//              rounds with benign races converge to the greedy answer.
// ---------------------------------------------------------------------------
__global__ __launch_bounds__(NMS_THREADS) void nms_kernel(
    const float* __restrict__ x, int* __restrict__ nsurv, Surv* __restrict__ surv)
{
    const int f   = blockIdx.x;
    const int tid = threadIdx.x;
    const float* __restrict__ e = x + (size_t)f * 2 * VOX;   // energy channel

    __shared__ float sval[KCAP];
    __shared__ int   sidx[KCAP];
    __shared__ short srank[KCAP];
    __shared__ unsigned char status[KCAP];     // 0 undecided, 1 kept, 2 suppressed
    __shared__ unsigned short pnbr[KCAP * NBRCAP];  // higher-priority conflicts
    __shared__ int s_cntpos, s_cntnz, s_nkept, s_out, s_undec;

    if (tid == 0) { s_cntpos = 0; s_cntnz = 0; s_nkept = 0; s_out = 0; }
    __syncthreads();

    // ---- Phase A: collect positive voxels (pure read; 16 waves of MLP) ----
    {
        const float4* e4 = (const float4*)e;
        int nzloc = 0;
        #pragma unroll
        for (int h = 0; h < VOX / 4 / NMS_THREADS; ++h) {
            int i = tid + h * NMS_THREADS;
            float4 v = e4[i];
            float vv[4] = {v.x, v.y, v.z, v.w};
            #pragma unroll
            for (int c = 0; c < 4; ++c) {
                float val = vv[c];
                if (val != 0.f) {
                    nzloc++;
                    if (val > 0.f) {
                        int slot = atomicAdd(&s_cntpos, 1);
                        if (slot < KCAP) { sval[slot] = val; sidx[slot] = i * 4 + c; }
                    }
                }
            }
        }
        if (nzloc) atomicAdd(&s_cntnz, nzloc);
    }
    __syncthreads();

    const int npos  = min(s_cntpos, KCAP);
    const int anynz = s_cntnz;

    // ---- Phase B+C fused: rank + higher-priority conflict list, 1 pt/thread
    int pcnt = 0;
    if (tid < npos) {
        const float vt = sval[tid];
        const int   it = sidx[tid];
        const int zt = it >> 10, yt = (it >> 5) & 31, xt = it & 31;
        int rank = 0;
        for (int i = 0; i < npos; ++i) {
            float vi = sval[i];          // wave-uniform i -> LDS broadcast
            int   ii = sidx[i];
            bool hp = (vi > vt) || (vi == vt && ii < it);  // self: false
            rank += hp;
            if (hp) {
                int dz = (ii >> 10)       - zt; if (dz < 0) dz = -dz;
                int dy = ((ii >> 5) & 31) - yt; if (dy < 0) dy = -dy;
                int dx = (ii & 31)        - xt; if (dx < 0) dx = -dx;
                if ((dz | dy | dx) <= 1) {          // Chebyshev <= 1
                    if (pcnt < NBRCAP) pnbr[tid * NBRCAP + pcnt] = (unsigned short)i;
                    pcnt++;
                }
            }
        }
        srank[tid]  = (short)rank;
        status[tid] = (pcnt == 0) ? (unsigned char)1 : (unsigned char)0;
    }
    __syncthreads();

    // ---- Phase D: parallel greedy resolution (monotone label propagation) ----
    for (int round = 0; round < KCAP; ++round) {
        if (tid == 0) s_undec = 0;
        __syncthreads();
        if (tid < npos && status[tid] == 0) {
            bool anyKept = false, anyUndec = false;
            for (int p = 0; p < pcnt; ++p) {
                unsigned char s = status[pnbr[tid * NBRCAP + p]];
                anyKept  |= (s == 1);
                anyUndec |= (s == 0);
            }
            if (anyKept)        status[tid] = 2;
            else if (!anyUndec) status[tid] = 1;
            else                s_undec = 1;        // benign race: all write 1
        }
        __syncthreads();
        if (s_undec == 0) break;
    }

    // ---- Phase E: count kept, apply rank truncation, compact survivors ----
    if (tid < npos && status[tid] == 1) atomicAdd(&s_nkept, 1);
    __syncthreads();
    const int nkept = s_nkept;
    if (tid < npos && status[tid] == 1 &&
        !(nkept > MAXEV && srank[tid] >= MAXEV)) {
        int slot = atomicAdd(&s_out, 1);
        Surv s; s.vox = sidx[tid]; s.val = sval[tid];
        surv[f * MAXSURV + slot] = s;
    }
    __syncthreads();
    if (tid == 0) nsurv[f] = anynz ? s_out : -1;
}

// ---------------------------------------------------------------------------
// Kernel 2: build output. Grid = frames*CHUNKS blocks; each block owns a
// 32 KB chunk of one frame's [2,V] output: zero it (or copy input for empty
// frames), then scatter the survivors that land in this chunk.
// ---------------------------------------------------------------------------
__global__ __launch_bounds__(OUT_THREADS) void output_kernel(
    const float* __restrict__ x, const int* __restrict__ nsurv,
    const Surv* __restrict__ surv, float* __restrict__ out)
{
    const int bid = blockIdx.x;
    const int f   = bid / CHUNKS;
    const int c   = bid % CHUNKS;
    const int tid = threadIdx.x;

    const float* __restrict__ xf = x   + (size_t)f * 2 * VOX;
    float*       __restrict__ of = out + (size_t)f * 2 * VOX;
    const int base = c * CHUNK_FLOATS;
    const int ns   = nsurv[f];

    if (ns < 0) {
        // empty frame: pass through input unchanged
        const float4* x4 = (const float4*)(xf + base);
        float4*       o4 = (float4*)(of + base);
        #pragma unroll
        for (int h = 0; h < CHUNK_FLOATS / 4 / OUT_THREADS; ++h)
            o4[tid + h * OUT_THREADS] = x4[tid + h * OUT_THREADS];
        return;
    }

    // zero this chunk
    {
        float4* o4 = (float4*)(of + base);
        const float4 z = make_float4(0.f, 0.f, 0.f, 0.f);
        #pragma unroll
        for (int h = 0; h < CHUNK_FLOATS / 4 / OUT_THREADS; ++h)
            o4[tid + h * OUT_THREADS] = z;
    }
    __syncthreads();   // order zero-fill before scatter within the block

    // scatter survivors that fall in this chunk (ns <= 100 < OUT_THREADS)
    if (tid < ns) {
        Surv s = surv[f * MAXSURV + tid];
        int vox = s.vox;
        int ec  = vox >> 13;                  // energy chunk index (8192 floats)
        if (c == ec) {
            of[vox] = s.val;                  // exact energy copy
        } else if (c == ec + CHUNKS / 2) {
            of[VOX + vox] = xf[VOX + vox];    // exact magnitude copy
        }
    }
}

extern "C" void kernel_launch(void* const* d_in, const int* in_sizes, int n_in,
                              void* d_out, int out_size, void* d_ws, size_t ws_size,
                              hipStream_t stream) {
    const float* x = (const float*)d_in[0];
    float* out = (float*)d_out;
    int frames = in_sizes[0] / (2 * VOX);   // B*T = 256

    int*  nsurv = (int*)d_ws;
    Surv* surv  = (Surv*)((char*)d_ws + 4096);   // frames*4 <= 4096, keep aligned

    nms_kernel<<<frames, NMS_THREADS, 0, stream>>>(x, nsurv, surv);
    output_kernel<<<frames * CHUNKS, OUT_THREADS, 0, stream>>>(x, nsurv, surv, out);
}

// Round 4
// 129.746 us; speedup vs baseline: 1.7254x; 1.3477x over previous
//
#include <hip/hip_runtime.h>
#include <stdint.h>

typedef unsigned long long u64;
typedef unsigned int u32;

#define VOX     32768      // 32*32*32
#define KCAP    512        // candidate cap (matches reference K; npos <= NPTS=400)
#define MAXEV   100        // max_events
#define NBRCAP  26         // geometric max conflicts per point (26-neighborhood)
#define NMS_THREADS 1024
#define OUT_THREADS 256
#define CHUNKS  8
#define CHUNK_FLOATS (2 * VOX / CHUNKS)   // 8192 floats = 32 KB per chunk
#define MAXSURV 128

struct Surv { int vox; float val; };

// dist < 2.0 on integer coords  <=>  Chebyshev distance <= 1 (3x3x3 cube)
//
// Priority key: (float_bits(val) << 32) | ~vox  — vals are > 0 so float bits
// are monotone; higher val => bigger key; tie => lower vox => bigger key.
// hp(i over t) <=> skey[i] > skey[t]. Keys unique (voxels unique).

// ---------------------------------------------------------------------------
// Kernel 1: per-frame NMS -> compact survivor list in workspace.
// nsurv[f] = -1 means "empty frame, pass through input unchanged".
// ---------------------------------------------------------------------------
__global__ __launch_bounds__(NMS_THREADS) void nms_kernel(
    const float* __restrict__ x, int* __restrict__ nsurv, Surv* __restrict__ surv)
{
    const int f   = blockIdx.x;
    const int tid = threadIdx.x;
    const float* __restrict__ e = x + (size_t)f * 2 * VOX;   // energy channel

    __shared__ unsigned short smap[VOX];            // voxel -> cand slot (0xFFFF = none), 64 KB
    __shared__ u64   skey[KCAP];                    // packed priority keys
    __shared__ short srank[KCAP];
    __shared__ unsigned char status[KCAP];          // 0 undecided, 1 kept, 2 suppressed
    __shared__ unsigned short pnbr[KCAP * NBRCAP];  // higher-priority conflicts
    __shared__ int s_cntpos, s_cntnz, s_nkept, s_out, s_undec;

    if (tid == 0) { s_cntpos = 0; s_cntnz = 0; s_nkept = 0; s_out = 0; }
    // init voxel map to "empty"
    {
        u32* m32 = (u32*)smap;
        #pragma unroll
        for (int h = 0; h < VOX / 2 / NMS_THREADS; ++h)
            m32[tid + h * NMS_THREADS] = 0xFFFFFFFFu;
    }
    __syncthreads();

    // ---- Phase A: read energy, build candidate list + dense voxel map ----
    {
        const float4* e4 = (const float4*)e;
        int nzloc = 0;
        #pragma unroll
        for (int h = 0; h < VOX / 4 / NMS_THREADS; ++h) {
            int i = tid + h * NMS_THREADS;
            float4 v = e4[i];
            float vv[4] = {v.x, v.y, v.z, v.w};
            #pragma unroll
            for (int c = 0; c < 4; ++c) {
                float val = vv[c];
                if (val > 0.f) {
                    nzloc++;
                    int slot = atomicAdd(&s_cntpos, 1);
                    if (slot < KCAP) {
                        int vox = i * 4 + c;
                        skey[slot] = ((u64)__float_as_uint(val) << 32) | (u64)(~(u32)vox);
                        smap[vox]  = (unsigned short)slot;
                    }
                } else if (val != 0.f) {
                    nzloc++;
                }
            }
        }
        if (nzloc) atomicAdd(&s_cntnz, nzloc);
    }
    __syncthreads();

    const int npos  = min(s_cntpos, KCAP);
    const int anynz = s_cntnz;

    // ---- Phase B: rank (tight all-pairs count, pipelineable: no stores) ----
    // ---- Phase C: neighbors via 26 direct map probes                    ----
    int pcnt = 0;
    if (tid < npos) {
        const u64 kt = skey[tid];

        int rank = 0;
        #pragma unroll 8
        for (int i = 0; i < npos; ++i)
            rank += (skey[i] > kt);        // same-address broadcast reads
        srank[tid] = (short)rank;

        const int vox = (int)(~(u32)kt) & (VOX - 1);
        const int zt = vox >> 10, yt = (vox >> 5) & 31, xt = vox & 31;
        #pragma unroll
        for (int dz = -1; dz <= 1; ++dz) {
            int z = zt + dz; if ((unsigned)z >= 32) continue;
            #pragma unroll
            for (int dy = -1; dy <= 1; ++dy) {
                int yy = yt + dy; if ((unsigned)yy >= 32) continue;
                #pragma unroll
                for (int dx = -1; dx <= 1; ++dx) {
                    int xx = xt + dx; if ((unsigned)xx >= 32) continue;
                    int nv = (z << 10) | (yy << 5) | xx;
                    if (nv == vox) continue;
                    unsigned short m = smap[nv];
                    if (m != 0xFFFFu && skey[m] > kt)
                        pnbr[tid * NBRCAP + pcnt++] = m;
                }
            }
        }
        status[tid] = (pcnt == 0) ? (unsigned char)1 : (unsigned char)0;
    }
    __syncthreads();

    // ---- Phase D: parallel greedy resolution (monotone label propagation) ----
    for (int round = 0; round < KCAP; ++round) {
        if (tid == 0) s_undec = 0;
        __syncthreads();
        if (tid < npos && status[tid] == 0) {
            bool anyKept = false, anyUndec = false;
            for (int p = 0; p < pcnt; ++p) {
                unsigned char s = status[pnbr[tid * NBRCAP + p]];
                anyKept  |= (s == 1);
                anyUndec |= (s == 0);
            }
            if (anyKept)        status[tid] = 2;
            else if (!anyUndec) status[tid] = 1;
            else                s_undec = 1;        // benign race: all write 1
        }
        __syncthreads();
        if (s_undec == 0) break;
    }

    // ---- Phase E: count kept, apply rank truncation, compact survivors ----
    if (tid < npos && status[tid] == 1) atomicAdd(&s_nkept, 1);
    __syncthreads();
    const int nkept = s_nkept;
    if (tid < npos && status[tid] == 1 &&
        !(nkept > MAXEV && srank[tid] >= MAXEV)) {
        int slot = atomicAdd(&s_out, 1);
        u64 kt = skey[tid];
        Surv s;
        s.vox = (int)(~(u32)kt) & (VOX - 1);
        s.val = __uint_as_float((u32)(kt >> 32));
        surv[f * MAXSURV + slot] = s;
    }
    __syncthreads();
    if (tid == 0) nsurv[f] = anynz ? s_out : -1;
}

// ---------------------------------------------------------------------------
// Kernel 2: build output. Grid = frames*CHUNKS blocks; each block owns a
// 32 KB chunk of one frame's [2,V] output: zero it (or copy input for empty
// frames), then scatter the survivors that land in this chunk.
// ---------------------------------------------------------------------------
__global__ __launch_bounds__(OUT_THREADS) void output_kernel(
    const float* __restrict__ x, const int* __restrict__ nsurv,
    const Surv* __restrict__ surv, float* __restrict__ out)
{
    const int bid = blockIdx.x;
    const int f   = bid / CHUNKS;
    const int c   = bid % CHUNKS;
    const int tid = threadIdx.x;

    const float* __restrict__ xf = x   + (size_t)f * 2 * VOX;
    float*       __restrict__ of = out + (size_t)f * 2 * VOX;
    const int base = c * CHUNK_FLOATS;
    const int ns   = nsurv[f];

    if (ns < 0) {
        // empty frame: pass through input unchanged
        const float4* x4 = (const float4*)(xf + base);
        float4*       o4 = (float4*)(of + base);
        #pragma unroll
        for (int h = 0; h < CHUNK_FLOATS / 4 / OUT_THREADS; ++h)
            o4[tid + h * OUT_THREADS] = x4[tid + h * OUT_THREADS];
        return;
    }

    // zero this chunk
    {
        float4* o4 = (float4*)(of + base);
        const float4 z = make_float4(0.f, 0.f, 0.f, 0.f);
        #pragma unroll
        for (int h = 0; h < CHUNK_FLOATS / 4 / OUT_THREADS; ++h)
            o4[tid + h * OUT_THREADS] = z;
    }
    __syncthreads();   // order zero-fill before scatter within the block

    // scatter survivors that fall in this chunk (ns <= 100 < OUT_THREADS)
    if (tid < ns) {
        Surv s = surv[f * MAXSURV + tid];
        int vox = s.vox;
        int ec  = vox >> 13;                  // energy chunk index (8192 floats)
        if (c == ec) {
            of[vox] = s.val;                  // exact energy copy
        } else if (c == ec + CHUNKS / 2) {
            of[VOX + vox] = xf[VOX + vox];    // exact magnitude copy
        }
    }
}

extern "C" void kernel_launch(void* const* d_in, const int* in_sizes, int n_in,
                              void* d_out, int out_size, void* d_ws, size_t ws_size,
                              hipStream_t stream) {
    const float* x = (const float*)d_in[0];
    float* out = (float*)d_out;
    int frames = in_sizes[0] / (2 * VOX);   // B*T = 256

    int*  nsurv = (int*)d_ws;
    Surv* surv  = (Surv*)((char*)d_ws + 4096);   // frames*4 <= 4096, keep aligned

    nms_kernel<<<frames, NMS_THREADS, 0, stream>>>(x, nsurv, surv);
    output_kernel<<<frames * CHUNKS, OUT_THREADS, 0, stream>>>(x, nsurv, surv, out);
}